// Round 1
// baseline (377.940 us; speedup 1.0000x reference)
//
#include <hip/hip_runtime.h>
#include <hip/hip_bf16.h>

#define B_ 8
#define T_ 2048
#define E_ 1024
#define H_ 64

__device__ __forceinline__ float bf_lo(unsigned u) { return __uint_as_float(u << 16); }
__device__ __forceinline__ float bf_hi(unsigned u) { return __uint_as_float(u & 0xffff0000u); }

// ---- projection: q,k,v = x @ {Wq,Wk,Wv}; q pre-scaled by E^-0.5; bf16 out ----
// grid: B*T/16 blocks, 256 threads; each block: 16 rows x 64 cols x 3 matrices
__global__ __launch_bounds__(256) void proj_kernel(
    const float* __restrict__ x, const float* __restrict__ Wk,
    const float* __restrict__ Wq, const float* __restrict__ Wv,
    __hip_bfloat16* __restrict__ Qb, __hip_bfloat16* __restrict__ Kb,
    __hip_bfloat16* __restrict__ Vb) {
  __shared__ float xs[16][128];
  const int tid = threadIdx.x;
  const int c = tid & 63;       // output col 0..63
  const int rq = tid >> 6;      // wave id 0..3 -> owns rows rq*4 .. rq*4+3
  const long row0 = (long)blockIdx.x * 16;
  float aq[4] = {0, 0, 0, 0}, ak[4] = {0, 0, 0, 0}, av[4] = {0, 0, 0, 0};
  for (int k0 = 0; k0 < E_; k0 += 128) {
    __syncthreads();
    {
      const int idx = tid * 8;          // 2048 floats = 16 rows x 128
      const int rr = idx >> 7, cc = idx & 127;
      const float4* src = reinterpret_cast<const float4*>(x + (row0 + rr) * E_ + k0 + cc);
      *reinterpret_cast<float4*>(&xs[rr][cc]) = src[0];
      *reinterpret_cast<float4*>(&xs[rr][cc + 4]) = src[1];
    }
    __syncthreads();
    #pragma unroll 4
    for (int kk = 0; kk < 128; ++kk) {
      const int widx = (k0 + kk) * H_ + c;
      const float wk = Wk[widx], wq = Wq[widx], wv = Wv[widx];
      #pragma unroll
      for (int r = 0; r < 4; ++r) {
        const float xv = xs[rq * 4 + r][kk];
        ak[r] += xv * wk;
        aq[r] += xv * wq;
        av[r] += xv * wv;
      }
    }
  }
  const float qscale = 0.03125f;  // 1024^-0.5
  #pragma unroll
  for (int r = 0; r < 4; ++r) {
    const long row = row0 + rq * 4 + r;
    Qb[row * H_ + c] = __float2bfloat16(aq[r] * qscale);
    Kb[row * H_ + c] = __float2bfloat16(ak[r]);
    Vb[row * H_ + c] = __float2bfloat16(av[r]);
  }
}

// ---- flash attention, causal, online softmax ----
// block: 256 threads = 4 waves; each wave owns 2 q-rows -> 8 rows/block
// grid: B * T/8 blocks
__global__ __launch_bounds__(256) void attn_kernel(
    const __hip_bfloat16* __restrict__ Qb, const __hip_bfloat16* __restrict__ Kb,
    const __hip_bfloat16* __restrict__ Vb, float* __restrict__ out) {
  __shared__ float Ks[64][H_ + 1];   // +1 pad: 2-way bank aliasing only (free)
  __shared__ float Vs[64][H_ + 1];
  __shared__ float qs[8][H_];
  __shared__ float ps[4][2][64];
  const int tid = threadIdx.x;
  const int lane = tid & 63;
  const int wave = tid >> 6;
  const int blk = blockIdx.x;
  const int b = blk >> 8;            // T/8 = 256 row-blocks per batch
  const int r0 = (blk & 255) * 8;
  const size_t base = (size_t)b * T_ * H_;

  for (int it = tid; it < 8 * H_; it += 256)
    qs[it >> 6][it & 63] = __bfloat162float(Qb[base + (size_t)r0 * H_ + it]);

  const int row0 = r0 + wave * 2;
  const int row1 = row0 + 1;
  float m0 = -1e30f, m1 = -1e30f, l0 = 0.f, l1 = 0.f, o0 = 0.f, o1 = 0.f;
  const int ntiles = (r0 >> 6) + 1;  // all tiles overlapping [0, r0+7]

  for (int t = 0; t < ntiles; ++t) {
    const int j0 = t * 64;
    __syncthreads();  // prior tile fully consumed (covers qs load at t=0)
    // stage K,V tile: 64 keys x 64 ch, bf16 -> f32
    for (int it = tid; it < 512; it += 256) {
      const int rr = it >> 3;
      const int cc = (it & 7) * 8;
      const size_t off = base + (size_t)(j0 + rr) * H_ + cc;
      const uint4 kr = *reinterpret_cast<const uint4*>(Kb + off);
      const uint4 vr = *reinterpret_cast<const uint4*>(Vb + off);
      float* kd = &Ks[rr][cc];
      kd[0] = bf_lo(kr.x); kd[1] = bf_hi(kr.x); kd[2] = bf_lo(kr.y); kd[3] = bf_hi(kr.y);
      kd[4] = bf_lo(kr.z); kd[5] = bf_hi(kr.z); kd[6] = bf_lo(kr.w); kd[7] = bf_hi(kr.w);
      float* vd = &Vs[rr][cc];
      vd[0] = bf_lo(vr.x); vd[1] = bf_hi(vr.x); vd[2] = bf_lo(vr.y); vd[3] = bf_hi(vr.y);
      vd[4] = bf_lo(vr.z); vd[5] = bf_hi(vr.z); vd[6] = bf_lo(vr.w); vd[7] = bf_hi(vr.w);
    }
    __syncthreads();

    // QK^T: lane owns key j0+lane
    float s0 = 0.f, s1 = 0.f;
    const float* q0p = qs[wave * 2];
    const float* q1p = qs[wave * 2 + 1];
    #pragma unroll
    for (int h = 0; h < H_; ++h) {
      const float kv = Ks[lane][h];
      s0 += q0p[h] * kv;
      s1 += q1p[h] * kv;
    }
    const int key = j0 + lane;
    if (key > row0) s0 = -1e30f;
    if (key > row1) s1 = -1e30f;

    // online softmax (per-row wave reductions)
    float pm0 = s0, pm1 = s1;
    #pragma unroll
    for (int off = 32; off; off >>= 1) {
      pm0 = fmaxf(pm0, __shfl_xor(pm0, off));
      pm1 = fmaxf(pm1, __shfl_xor(pm1, off));
    }
    const float nm0 = fmaxf(m0, pm0), nm1 = fmaxf(m1, pm1);
    const float a0 = __expf(m0 - nm0), a1 = __expf(m1 - nm1);
    const float p0 = __expf(s0 - nm0), p1 = __expf(s1 - nm1);
    m0 = nm0; m1 = nm1;
    float t0 = p0, t1 = p1;
    #pragma unroll
    for (int off = 32; off; off >>= 1) {
      t0 += __shfl_xor(t0, off);
      t1 += __shfl_xor(t1, off);
    }
    l0 = l0 * a0 + t0;
    l1 = l1 * a1 + t1;
    ps[wave][0][lane] = p0;
    ps[wave][1][lane] = p1;
    o0 *= a0; o1 *= a1;
    __syncthreads();  // ps visible (and Ks reads done before next staging)

    // PV: lane owns output channel `lane`
    const float* pp0 = ps[wave][0];
    const float* pp1 = ps[wave][1];
    #pragma unroll
    for (int j = 0; j < 64; ++j) {
      const float vv = Vs[j][lane];
      o0 += pp0[j] * vv;
      o1 += pp1[j] * vv;
    }
  }
  out[base + (size_t)row0 * H_ + lane] = o0 / l0;
  out[base + (size_t)row1 * H_ + lane] = o1 / l1;
}

extern "C" void kernel_launch(void* const* d_in, const int* in_sizes, int n_in,
                              void* d_out, int out_size, void* d_ws, size_t ws_size,
                              hipStream_t stream) {
  const float* x  = (const float*)d_in[0];
  const float* Wk = (const float*)d_in[1];
  const float* Wq = (const float*)d_in[2];
  const float* Wv = (const float*)d_in[3];
  float* out = (float*)d_out;

  __hip_bfloat16* Qb = (__hip_bfloat16*)d_ws;
  __hip_bfloat16* Kb = Qb + (size_t)B_ * T_ * H_;
  __hip_bfloat16* Vb = Kb + (size_t)B_ * T_ * H_;

  proj_kernel<<<B_ * T_ / 16, 256, 0, stream>>>(x, Wk, Wq, Wv, Qb, Kb, Vb);
  attn_kernel<<<B_ * (T_ / 8), 256, 0, stream>>>(Qb, Kb, Vb, out);
}

// Round 2
// 123.485 us; speedup vs baseline: 3.0606x; 3.0606x over previous
//
#include <hip/hip_runtime.h>
#include <hip/hip_bf16.h>

#define B_ 8
#define T_ 2048
#define E_ 1024
#define H_ 64

typedef __attribute__((ext_vector_type(8))) short short8v;
typedef __attribute__((ext_vector_type(4))) float f32x4;

__device__ __forceinline__ unsigned short bfbits(float f) {
  return __builtin_bit_cast(unsigned short, __float2bfloat16(f));
}

// ---- prep: Wt[m][c][k] = Wm[k][c] (bf16), q-scale folded into m==1 ----
__global__ __launch_bounds__(256) void prep_wt(
    const float* __restrict__ Wk, const float* __restrict__ Wq,
    const float* __restrict__ Wv, __hip_bfloat16* __restrict__ Wt) {
  const int idx = blockIdx.x * 256 + threadIdx.x;  // 3*64*1024 = 196608
  const int k = idx & 1023;
  const int c = (idx >> 10) & 63;
  const int m = idx >> 16;
  const float* W = (m == 0) ? Wk : (m == 1) ? Wq : Wv;
  float v = W[k * H_ + c];
  if (m == 1) v *= 0.03125f;  // 1024^-0.5
  Wt[idx] = __float2bfloat16(v);
}

// ---- projection via MFMA: block = 4 waves x 16 rows = 64 rows, all 192 cols ----
__global__ __launch_bounds__(256) void proj_mfma(
    const float* __restrict__ x, const __hip_bfloat16* __restrict__ Wt,
    __hip_bfloat16* __restrict__ Qb, __hip_bfloat16* __restrict__ Kb,
    __hip_bfloat16* __restrict__ Vt) {
  __shared__ __hip_bfloat16 rep[4][16][72];
  const int tid = threadIdx.x;
  const int lane = tid & 63;
  const int w = tid >> 6;
  const int r = lane & 15;   // A row / C col
  const int g = lane >> 4;   // k-group / C row group
  const long r0 = (long)blockIdx.x * 64 + w * 16;

  f32x4 acc[12];  // [m(K,Q,V)][cg 0..3]
  #pragma unroll
  for (int i = 0; i < 12; ++i) acc[i] = (f32x4){0.f, 0.f, 0.f, 0.f};

  const float* xrow = x + (r0 + r) * E_;
  for (int kc = 0; kc < E_; kc += 32) {
    const float4 a0 = *reinterpret_cast<const float4*>(xrow + kc + g * 8);
    const float4 a1 = *reinterpret_cast<const float4*>(xrow + kc + g * 8 + 4);
    short8v af;
    af[0] = (short)bfbits(a0.x); af[1] = (short)bfbits(a0.y);
    af[2] = (short)bfbits(a0.z); af[3] = (short)bfbits(a0.w);
    af[4] = (short)bfbits(a1.x); af[5] = (short)bfbits(a1.y);
    af[6] = (short)bfbits(a1.z); af[7] = (short)bfbits(a1.w);
    #pragma unroll
    for (int m = 0; m < 3; ++m) {
      #pragma unroll
      for (int cg = 0; cg < 4; ++cg) {
        const short8v bf = *reinterpret_cast<const short8v*>(
            Wt + (size_t)(m * 64 + cg * 16 + r) * E_ + kc + g * 8);
        acc[m * 4 + cg] =
            __builtin_amdgcn_mfma_f32_16x16x32_bf16(af, bf, acc[m * 4 + cg], 0, 0, 0);
      }
    }
  }

  // K (m=0), Q (m=1): repack C-frag -> row-major [t][64] via per-wave LDS
  #pragma unroll
  for (int m = 0; m < 2; ++m) {
    __hip_bfloat16* Pout = (m == 0) ? Kb : Qb;
    #pragma unroll
    for (int cg = 0; cg < 4; ++cg)
      #pragma unroll
      for (int reg = 0; reg < 4; ++reg)
        rep[w][g * 4 + reg][cg * 16 + r] =
            __float2bfloat16(acc[m * 4 + cg][reg]);
    #pragma unroll
    for (int i = 0; i < 2; ++i) {
      const int gg = i * 64 + lane;
      const int row = gg >> 3, c8 = (gg & 7) * 8;
      *reinterpret_cast<uint4*>(Pout + (r0 + row) * H_ + c8) =
          *reinterpret_cast<const uint4*>(&rep[w][row][c8]);
    }
  }
  // V: write transposed Vt[b][h][t], packing 4 consecutive t (regs) as 8B
  const int b = (int)(r0 >> 11);
  const int tt0 = (int)(r0 & 2047) + g * 4;
  #pragma unroll
  for (int cg = 0; cg < 4; ++cg) {
    const int h = cg * 16 + r;
    ushort4 pk;
    pk.x = bfbits(acc[8 + cg][0]);
    pk.y = bfbits(acc[8 + cg][1]);
    pk.z = bfbits(acc[8 + cg][2]);
    pk.w = bfbits(acc[8 + cg][3]);
    *reinterpret_cast<ushort4*>(Vt + (size_t)(b * 64 + h) * T_ + tt0) = pk;
  }
}

// ---- flash attention via MFMA: 2 waves x 16 q-rows, KBLK=64 ----
__global__ __launch_bounds__(128) void attn_mfma(
    const __hip_bfloat16* __restrict__ Qb, const __hip_bfloat16* __restrict__ Kb,
    const __hip_bfloat16* __restrict__ Vt, float* __restrict__ out) {
  __shared__ __hip_bfloat16 Ks[64][72];        // [key][h], +8 pad
  __shared__ __hip_bfloat16 Vs[64][72];        // [h][key], +8 pad
  __shared__ __hip_bfloat16 Ps[2][16][72];     // per-wave P
  const int tid = threadIdx.x;
  const int lane = tid & 63;
  const int w = tid >> 6;
  const int r = lane & 15, g = lane >> 4;
  const int blk = blockIdx.x;
  const int b = blk >> 6;
  const int qt = blk & 63;
  const int q0 = qt * 32 + w * 16;
  const size_t tb = (size_t)b * T_;

  const short8v qf0 = *reinterpret_cast<const short8v*>(Qb + (tb + q0 + r) * H_ + g * 8);
  const short8v qf1 = *reinterpret_cast<const short8v*>(Qb + (tb + q0 + r) * H_ + 32 + g * 8);

  f32x4 o[4];
  #pragma unroll
  for (int i = 0; i < 4; ++i) o[i] = (f32x4){0.f, 0.f, 0.f, 0.f};
  float mrun[4] = {-1e30f, -1e30f, -1e30f, -1e30f};
  float lrun[4] = {0.f, 0.f, 0.f, 0.f};

  const int ntiles = (qt >> 1) + 1;
  for (int t = 0; t < ntiles; ++t) {
    const int j0 = t * 64;
    __syncthreads();  // previous tile fully consumed
    #pragma unroll
    for (int i = 0; i < 4; ++i) {
      const int gg = i * 128 + tid;
      const int row = gg >> 3, c8 = (gg & 7) * 8;
      *reinterpret_cast<uint4*>(&Ks[row][c8]) =
          *reinterpret_cast<const uint4*>(Kb + (tb + j0 + row) * H_ + c8);
      *reinterpret_cast<uint4*>(&Vs[row][c8]) =
          *reinterpret_cast<const uint4*>(Vt + (size_t)(b * 64 + row) * T_ + j0 + c8);
    }
    __syncthreads();

    // QK^T: s[kg] covers keys j0+kg*16..+15 x 16 q-rows
    f32x4 s[4];
    #pragma unroll
    for (int i = 0; i < 4; ++i) s[i] = (f32x4){0.f, 0.f, 0.f, 0.f};
    #pragma unroll
    for (int kg = 0; kg < 4; ++kg) {
      const short8v kb0 = *reinterpret_cast<const short8v*>(&Ks[kg * 16 + r][g * 8]);
      const short8v kb1 = *reinterpret_cast<const short8v*>(&Ks[kg * 16 + r][32 + g * 8]);
      s[kg] = __builtin_amdgcn_mfma_f32_16x16x32_bf16(qf0, kb0, s[kg], 0, 0, 0);
      s[kg] = __builtin_amdgcn_mfma_f32_16x16x32_bf16(qf1, kb1, s[kg], 0, 0, 0);
    }
    if (t == ntiles - 1) {  // only last tile can cross the diagonal
      #pragma unroll
      for (int kg = 0; kg < 4; ++kg) {
        const int key = j0 + kg * 16 + r;
        #pragma unroll
        for (int reg = 0; reg < 4; ++reg)
          if (key > q0 + g * 4 + reg) s[kg][reg] = -1e30f;
      }
    }

    // online softmax; row = q0 + g*4 + reg, cols spread over (kg, lane&15)
    float p[4][4];
    #pragma unroll
    for (int reg = 0; reg < 4; ++reg) {
      float pm = fmaxf(fmaxf(s[0][reg], s[1][reg]), fmaxf(s[2][reg], s[3][reg]));
      pm = fmaxf(pm, __shfl_xor(pm, 1));
      pm = fmaxf(pm, __shfl_xor(pm, 2));
      pm = fmaxf(pm, __shfl_xor(pm, 4));
      pm = fmaxf(pm, __shfl_xor(pm, 8));
      const float nm = fmaxf(mrun[reg], pm);
      const float al = __expf(mrun[reg] - nm);
      mrun[reg] = nm;
      float rs = 0.f;
      #pragma unroll
      for (int kg = 0; kg < 4; ++kg) {
        p[kg][reg] = __expf(s[kg][reg] - nm);
        rs += p[kg][reg];
      }
      rs += __shfl_xor(rs, 1);
      rs += __shfl_xor(rs, 2);
      rs += __shfl_xor(rs, 4);
      rs += __shfl_xor(rs, 8);
      lrun[reg] = lrun[reg] * al + rs;
      o[0][reg] *= al; o[1][reg] *= al; o[2][reg] *= al; o[3][reg] *= al;
    }

    // P -> per-wave LDS (A-frag layout), then PV
    #pragma unroll
    for (int kg = 0; kg < 4; ++kg)
      #pragma unroll
      for (int reg = 0; reg < 4; ++reg)
        Ps[w][g * 4 + reg][kg * 16 + r] = __float2bfloat16(p[kg][reg]);
    #pragma unroll
    for (int kc = 0; kc < 2; ++kc) {
      const short8v pf = *reinterpret_cast<const short8v*>(&Ps[w][r][kc * 32 + g * 8]);
      #pragma unroll
      for (int hg = 0; hg < 4; ++hg) {
        const short8v vf = *reinterpret_cast<const short8v*>(&Vs[hg * 16 + r][kc * 32 + g * 8]);
        o[hg] = __builtin_amdgcn_mfma_f32_16x16x32_bf16(pf, vf, o[hg], 0, 0, 0);
      }
    }
  }

  #pragma unroll
  for (int hg = 0; hg < 4; ++hg)
    #pragma unroll
    for (int reg = 0; reg < 4; ++reg)
      out[(tb + q0 + g * 4 + reg) * H_ + hg * 16 + r] = o[hg][reg] / lrun[reg];
}

extern "C" void kernel_launch(void* const* d_in, const int* in_sizes, int n_in,
                              void* d_out, int out_size, void* d_ws, size_t ws_size,
                              hipStream_t stream) {
  const float* x  = (const float*)d_in[0];
  const float* Wk = (const float*)d_in[1];
  const float* Wq = (const float*)d_in[2];
  const float* Wv = (const float*)d_in[3];
  float* out = (float*)d_out;

  __hip_bfloat16* Qb = (__hip_bfloat16*)d_ws;
  __hip_bfloat16* Kb = Qb + (size_t)B_ * T_ * H_;
  __hip_bfloat16* Vt = Kb + (size_t)B_ * T_ * H_;   // [B][64][T]
  __hip_bfloat16* Wt = Vt + (size_t)B_ * T_ * H_;   // [3][64][1024]

  prep_wt<<<(3 * H_ * E_) / 256, 256, 0, stream>>>(Wk, Wq, Wv, Wt);
  proj_mfma<<<(B_ * T_) / 64, 256, 0, stream>>>(x, Wt, Qb, Kb, Vt);
  attn_mfma<<<B_ * (T_ / 32), 128, 0, stream>>>(Qb, Kb, Vt, out);
}

// Round 3
// 109.523 us; speedup vs baseline: 3.4508x; 1.1275x over previous
//
#include <hip/hip_runtime.h>
#include <hip/hip_bf16.h>

#define B_ 8
#define T_ 2048
#define E_ 1024
#define H_ 64

typedef __attribute__((ext_vector_type(8))) short short8v;
typedef __attribute__((ext_vector_type(4))) float f32x4;

__device__ __forceinline__ unsigned short bfbits(float f) {
  return __builtin_bit_cast(unsigned short, __float2bfloat16(f));
}

__device__ __forceinline__ void gload_lds16(const void* g, void* l) {
  __builtin_amdgcn_global_load_lds(
      (const __attribute__((address_space(1))) unsigned*)g,
      (__attribute__((address_space(3))) unsigned*)l, 16, 0, 0);
}

// ---- prep: Wt[m][c][k] = Wm[k][c] (bf16), q-scale folded into m==1 ----
__global__ __launch_bounds__(256) void prep_wt(
    const float* __restrict__ Wk, const float* __restrict__ Wq,
    const float* __restrict__ Wv, __hip_bfloat16* __restrict__ Wt) {
  const int idx = blockIdx.x * 256 + threadIdx.x;  // 3*64*1024
  const int k = idx & 1023;
  const int c = (idx >> 10) & 63;
  const int m = idx >> 16;
  const float* W = (m == 0) ? Wk : (m == 1) ? Wq : Wv;
  float v = W[k * H_ + c];
  if (m == 1) v *= 0.03125f;  // 1024^-0.5
  Wt[idx] = __float2bfloat16(v);
}

// ---- projection: 32 rows/block, 192 cols, BK=64, double-buffered LDS ----
// wave w owns col-tile w (16 cols) of each of K,Q,V; 2 row-tiles of 16.
__global__ __launch_bounds__(256) void proj_mfma(
    const float* __restrict__ x, const __hip_bfloat16* __restrict__ Wt,
    __hip_bfloat16* __restrict__ Qb, __hip_bfloat16* __restrict__ Kb,
    __hip_bfloat16* __restrict__ Vt) {
  __shared__ float xs[2][32][64];            // 16 KB, slot16-swizzled by row&7
  __shared__ __hip_bfloat16 Ws[2][192][64];  // 48 KB, slot16-swizzled by row&7
  const int tid = threadIdx.x;
  const int lane = tid & 63;
  const int w = tid >> 6;
  const int r = lane & 15, g = lane >> 4;
  const int r0 = blockIdx.x * 32;

  f32x4 acc[3][2];
  #pragma unroll
  for (int m = 0; m < 3; ++m)
    #pragma unroll
    for (int rt = 0; rt < 2; ++rt) acc[m][rt] = (f32x4){0.f, 0.f, 0.f, 0.f};

  auto stage = [&](int buf, int kc) {
    // x tile: 8 KB, 8 gl_lds (2/wave); pre-swizzled source, linear LDS dest
    #pragma unroll
    for (int jj = 0; jj < 2; ++jj) {
      const int jb = w * 2 + jj;
      const int row = jb * 4 + (lane >> 4);
      const int sl = lane & 15;
      const int ssl = (sl & 8) | ((sl & 7) ^ (row & 7));
      gload_lds16(x + (size_t)(r0 + row) * E_ + kc + ssl * 4, &xs[buf][jb * 4][0]);
    }
    // W tile: 24 KB, 24 gl_lds (6/wave)
    #pragma unroll
    for (int jj = 0; jj < 6; ++jj) {
      const int jb = w * 6 + jj;
      const int row = jb * 8 + (lane >> 3);
      const int sl = (lane & 7) ^ (row & 7);
      gload_lds16(Wt + (size_t)row * E_ + kc + sl * 8, &Ws[buf][jb * 8][0]);
    }
  };

  auto compute = [&](int buf) {
    #pragma unroll
    for (int kh = 0; kh < 2; ++kh) {
      short8v a[2];
      #pragma unroll
      for (int rt = 0; rt < 2; ++rt) {
        const int row = rt * 16 + r;
        const char* base = (const char*)&xs[buf][0][0] + row * 256;
        const int s0 = kh * 8 + ((2 * g + 0) ^ (r & 7));
        const int s1 = kh * 8 + ((2 * g + 1) ^ (r & 7));
        const f32x4 lo = *(const f32x4*)(base + s0 * 16);
        const f32x4 hi = *(const f32x4*)(base + s1 * 16);
        short8v t8;
        t8[0] = (short)bfbits(lo[0]); t8[1] = (short)bfbits(lo[1]);
        t8[2] = (short)bfbits(lo[2]); t8[3] = (short)bfbits(lo[3]);
        t8[4] = (short)bfbits(hi[0]); t8[5] = (short)bfbits(hi[1]);
        t8[6] = (short)bfbits(hi[2]); t8[7] = (short)bfbits(hi[3]);
        a[rt] = t8;
      }
      #pragma unroll
      for (int m = 0; m < 3; ++m) {
        const int row = m * 64 + w * 16 + r;
        const int sl = (kh * 4 + g) ^ (r & 7);
        const short8v bf =
            *(const short8v*)((const char*)&Ws[buf][0][0] + row * 128 + sl * 16);
        #pragma unroll
        for (int rt = 0; rt < 2; ++rt)
          acc[m][rt] = __builtin_amdgcn_mfma_f32_16x16x32_bf16(a[rt], bf, acc[m][rt], 0, 0, 0);
      }
    }
  };

  stage(0, 0);
  asm volatile("s_waitcnt vmcnt(0)" ::: "memory");
  __syncthreads();
  for (int t = 0; t < 16; ++t) {
    const int buf = t & 1;
    if (t < 15) stage(buf ^ 1, (t + 1) * 64);
    compute(buf);
    asm volatile("s_waitcnt vmcnt(0)" ::: "memory");
    __syncthreads();
  }

  // epilogue: reuse xs as per-wave repack space (32 rows x 24 cols bf16)
  __hip_bfloat16* rep = (__hip_bfloat16*)&xs[0][0][0] + w * (32 * 24);
  #pragma unroll
  for (int m = 0; m < 2; ++m) {
    __hip_bfloat16* Pout = (m == 0) ? Kb : Qb;
    #pragma unroll
    for (int rt = 0; rt < 2; ++rt)
      #pragma unroll
      for (int reg = 0; reg < 4; ++reg)
        rep[(rt * 16 + g * 4 + reg) * 24 + r] = __float2bfloat16(acc[m][rt][reg]);
    asm volatile("s_waitcnt lgkmcnt(0)" ::: "memory");
    __builtin_amdgcn_sched_barrier(0);
    {
      const int row = lane >> 1, ch = lane & 1;
      *(uint4*)(Pout + (size_t)(r0 + row) * H_ + w * 16 + ch * 8) =
          *(const uint4*)(rep + row * 24 + ch * 8);
    }
    asm volatile("s_waitcnt lgkmcnt(0)" ::: "memory");
    __builtin_amdgcn_sched_barrier(0);
  }
  // V: direct transposed write Vt[b][h][t]
  const int b = r0 >> 11;
  const int tt = r0 & 2047;
  #pragma unroll
  for (int rt = 0; rt < 2; ++rt) {
    ushort4 pk;
    pk.x = bfbits(acc[2][rt][0]); pk.y = bfbits(acc[2][rt][1]);
    pk.z = bfbits(acc[2][rt][2]); pk.w = bfbits(acc[2][rt][3]);
    *(ushort4*)(Vt + (size_t)(b * 64 + w * 16 + r) * T_ + tt + rt * 16 + g * 4) = pk;
  }
}

// ---- flash attention via MFMA: 2 waves x 16 q-rows, KBLK=64, dbuf+prefetch ----
__global__ __launch_bounds__(128) void attn_mfma(
    const __hip_bfloat16* __restrict__ Qb, const __hip_bfloat16* __restrict__ Kb,
    const __hip_bfloat16* __restrict__ Vt, float* __restrict__ out) {
  __shared__ __hip_bfloat16 Ks[2][64][72];
  __shared__ __hip_bfloat16 Vs[2][64][72];
  __shared__ __hip_bfloat16 Ps[2][16][72];
  const int tid = threadIdx.x;
  const int lane = tid & 63;
  const int w = tid >> 6;
  const int r = lane & 15, g = lane >> 4;
  const int blk = blockIdx.x;
  const int b = blk & 7;
  const int i = blk >> 3;                       // 0..63
  const int qt = (i < 32) ? (i * 2) : (127 - i * 2);  // causal load balance
  const int q0 = qt * 32 + w * 16;
  const size_t tb = (size_t)b * T_;

  const short8v qf0 = *reinterpret_cast<const short8v*>(Qb + (tb + q0 + r) * H_ + g * 8);
  const short8v qf1 = *reinterpret_cast<const short8v*>(Qb + (tb + q0 + r) * H_ + 32 + g * 8);

  f32x4 o[4];
  #pragma unroll
  for (int i2 = 0; i2 < 4; ++i2) o[i2] = (f32x4){0.f, 0.f, 0.f, 0.f};
  float mrun[4] = {-1e30f, -1e30f, -1e30f, -1e30f};
  float lrun[4] = {0.f, 0.f, 0.f, 0.f};

  uint4 kreg[4], vreg[4];
  auto issue = [&](int j0) {
    #pragma unroll
    for (int ii = 0; ii < 4; ++ii) {
      const int gg = ii * 128 + tid;
      const int row = gg >> 3, c8 = (gg & 7) * 8;
      kreg[ii] = *(const uint4*)(Kb + (tb + j0 + row) * H_ + c8);
      vreg[ii] = *(const uint4*)(Vt + (size_t)(b * 64 + row) * T_ + j0 + c8);
    }
  };
  auto commit = [&](int buf) {
    #pragma unroll
    for (int ii = 0; ii < 4; ++ii) {
      const int gg = ii * 128 + tid;
      const int row = gg >> 3, c8 = (gg & 7) * 8;
      *(uint4*)&Ks[buf][row][c8] = kreg[ii];
      *(uint4*)&Vs[buf][row][c8] = vreg[ii];
    }
  };

  const int ntiles = (qt >> 1) + 1;
  issue(0);
  commit(0);
  __syncthreads();

  for (int t = 0; t < ntiles; ++t) {
    const int buf = t & 1;
    const int j0 = t * 64;
    if (t + 1 < ntiles) issue(j0 + 64);

    // QK^T
    f32x4 s[4];
    #pragma unroll
    for (int i2 = 0; i2 < 4; ++i2) s[i2] = (f32x4){0.f, 0.f, 0.f, 0.f};
    #pragma unroll
    for (int kg = 0; kg < 4; ++kg) {
      const short8v kb0 = *(const short8v*)&Ks[buf][kg * 16 + r][g * 8];
      const short8v kb1 = *(const short8v*)&Ks[buf][kg * 16 + r][32 + g * 8];
      s[kg] = __builtin_amdgcn_mfma_f32_16x16x32_bf16(qf0, kb0, s[kg], 0, 0, 0);
      s[kg] = __builtin_amdgcn_mfma_f32_16x16x32_bf16(qf1, kb1, s[kg], 0, 0, 0);
    }
    if (t == ntiles - 1) {  // only diagonal tile crosses the causal boundary
      #pragma unroll
      for (int kg = 0; kg < 4; ++kg) {
        const int key = j0 + kg * 16 + r;
        #pragma unroll
        for (int reg = 0; reg < 4; ++reg)
          if (key > q0 + g * 4 + reg) s[kg][reg] = -1e30f;
      }
    }

    // online softmax; row = q0+g*4+reg, cols over (kg, r)
    float p[4][4];
    #pragma unroll
    for (int reg = 0; reg < 4; ++reg) {
      float pm = fmaxf(fmaxf(s[0][reg], s[1][reg]), fmaxf(s[2][reg], s[3][reg]));
      pm = fmaxf(pm, __shfl_xor(pm, 1));
      pm = fmaxf(pm, __shfl_xor(pm, 2));
      pm = fmaxf(pm, __shfl_xor(pm, 4));
      pm = fmaxf(pm, __shfl_xor(pm, 8));
      const float nm = fmaxf(mrun[reg], pm);
      const float al = __expf(mrun[reg] - nm);
      mrun[reg] = nm;
      float rs = 0.f;
      #pragma unroll
      for (int kg = 0; kg < 4; ++kg) {
        p[kg][reg] = __expf(s[kg][reg] - nm);
        rs += p[kg][reg];
      }
      rs += __shfl_xor(rs, 1);
      rs += __shfl_xor(rs, 2);
      rs += __shfl_xor(rs, 4);
      rs += __shfl_xor(rs, 8);
      lrun[reg] = lrun[reg] * al + rs;
      o[0][reg] *= al; o[1][reg] *= al; o[2][reg] *= al; o[3][reg] *= al;
    }

    // P -> per-wave LDS (A-frag layout); wave-local, no block barrier needed
    #pragma unroll
    for (int kg = 0; kg < 4; ++kg)
      #pragma unroll
      for (int reg = 0; reg < 4; ++reg)
        Ps[w][g * 4 + reg][kg * 16 + r] = __float2bfloat16(p[kg][reg]);
    asm volatile("s_waitcnt lgkmcnt(0)" ::: "memory");
    __builtin_amdgcn_sched_barrier(0);

    // PV
    #pragma unroll
    for (int kc = 0; kc < 2; ++kc) {
      const short8v pf = *(const short8v*)&Ps[w][r][kc * 32 + g * 8];
      #pragma unroll
      for (int hg = 0; hg < 4; ++hg) {
        const short8v vf = *(const short8v*)&Vs[buf][hg * 16 + r][kc * 32 + g * 8];
        o[hg] = __builtin_amdgcn_mfma_f32_16x16x32_bf16(pf, vf, o[hg], 0, 0, 0);
      }
    }

    if (t + 1 < ntiles) commit(buf ^ 1);
    __syncthreads();  // single barrier: staging of buf^1 visible to both waves
  }

  #pragma unroll
  for (int hg = 0; hg < 4; ++hg)
    #pragma unroll
    for (int reg = 0; reg < 4; ++reg)
      out[(tb + q0 + g * 4 + reg) * H_ + hg * 16 + r] = o[hg][reg] / lrun[reg];
}

extern "C" void kernel_launch(void* const* d_in, const int* in_sizes, int n_in,
                              void* d_out, int out_size, void* d_ws, size_t ws_size,
                              hipStream_t stream) {
  const float* x  = (const float*)d_in[0];
  const float* Wk = (const float*)d_in[1];
  const float* Wq = (const float*)d_in[2];
  const float* Wv = (const float*)d_in[3];
  float* out = (float*)d_out;

  __hip_bfloat16* Qb = (__hip_bfloat16*)d_ws;
  __hip_bfloat16* Kb = Qb + (size_t)B_ * T_ * H_;
  __hip_bfloat16* Vt = Kb + (size_t)B_ * T_ * H_;   // [B][64][T]
  __hip_bfloat16* Wt = Vt + (size_t)B_ * T_ * H_;   // [3][64][1024]

  prep_wt<<<(3 * H_ * E_) / 256, 256, 0, stream>>>(Wk, Wq, Wv, Wt);
  proj_mfma<<<(B_ * T_) / 32, 256, 0, stream>>>(x, Wt, Qb, Kb, Vt);
  attn_mfma<<<B_ * (T_ / 32), 128, 0, stream>>>(Qb, Kb, Vt, out);
}

// Round 4
// 78.973 us; speedup vs baseline: 4.7857x; 1.3869x over previous
//
#include <hip/hip_runtime.h>
#include <hip/hip_bf16.h>

#define B_ 8
#define T_ 2048
#define E_ 1024
#define H_ 64

typedef __attribute__((ext_vector_type(8))) short short8v;
typedef __attribute__((ext_vector_type(4))) float f32x4;

__device__ __forceinline__ unsigned short bfbits(float f) {
  return __builtin_bit_cast(unsigned short, __float2bfloat16(f));
}

__device__ __forceinline__ void gload_lds16(const void* g, void* l) {
  __builtin_amdgcn_global_load_lds(
      (const __attribute__((address_space(1))) unsigned*)g,
      (__attribute__((address_space(3))) unsigned*)l, 16, 0, 0);
}

// ---- prep: Wt[m][c][k] = Wm[k][c] (bf16), q-scale folded into m==1 ----
__global__ __launch_bounds__(256) void prep_wt(
    const float* __restrict__ Wk, const float* __restrict__ Wq,
    const float* __restrict__ Wv, __hip_bfloat16* __restrict__ Wt) {
  const int idx = blockIdx.x * 256 + threadIdx.x;  // 3*64*1024
  const int k = idx & 1023;
  const int c = (idx >> 10) & 63;
  const int m = idx >> 16;
  const float* W = (m == 0) ? Wk : (m == 1) ? Wq : Wv;
  float v = W[k * H_ + c];
  if (m == 1) v *= 0.03125f;  // 1024^-0.5
  Wt[idx] = __float2bfloat16(v);
}

// ---- projection: 32 rows/block, BK=64; x via gload_lds dbuf, W direct from L2 ----
__global__ __launch_bounds__(256) void proj_mfma(
    const float* __restrict__ x, const __hip_bfloat16* __restrict__ Wt,
    __hip_bfloat16* __restrict__ Qb, __hip_bfloat16* __restrict__ Kb,
    __hip_bfloat16* __restrict__ Vt) {
  __shared__ float xs[2][32][64];  // 16 KB, slot16-swizzled by row&7
  const int tid = threadIdx.x;
  const int lane = tid & 63;
  const int w = tid >> 6;
  const int r = lane & 15, g = lane >> 4;
  const int r0 = blockIdx.x * 32;

  f32x4 acc[3][2];
  #pragma unroll
  for (int m = 0; m < 3; ++m)
    #pragma unroll
    for (int rt = 0; rt < 2; ++rt) acc[m][rt] = (f32x4){0.f, 0.f, 0.f, 0.f};

  auto stage = [&](int buf, int kc) {
    #pragma unroll
    for (int jj = 0; jj < 2; ++jj) {
      const int jb = w * 2 + jj;
      const int row = jb * 4 + (lane >> 4);
      const int sl = lane & 15;
      const int ssl = (sl & 8) | ((sl & 7) ^ (row & 7));
      gload_lds16(x + (size_t)(r0 + row) * E_ + kc + ssl * 4, &xs[buf][jb * 4][0]);
    }
  };

  auto compute = [&](int buf, int kc) {
    #pragma unroll
    for (int kh = 0; kh < 2; ++kh) {
      short8v a[2];
      #pragma unroll
      for (int rt = 0; rt < 2; ++rt) {
        const int row = rt * 16 + r;
        const char* base = (const char*)&xs[buf][0][0] + row * 256;
        const int s0 = kh * 8 + ((2 * g + 0) ^ (r & 7));
        const int s1 = kh * 8 + ((2 * g + 1) ^ (r & 7));
        const f32x4 lo = *(const f32x4*)(base + s0 * 16);
        const f32x4 hi = *(const f32x4*)(base + s1 * 16);
        short8v t8;
        t8[0] = (short)bfbits(lo[0]); t8[1] = (short)bfbits(lo[1]);
        t8[2] = (short)bfbits(lo[2]); t8[3] = (short)bfbits(lo[3]);
        t8[4] = (short)bfbits(hi[0]); t8[5] = (short)bfbits(hi[1]);
        t8[6] = (short)bfbits(hi[2]); t8[7] = (short)bfbits(hi[3]);
        a[rt] = t8;
      }
      #pragma unroll
      for (int m = 0; m < 3; ++m) {
        const short8v bf = *(const short8v*)(
            Wt + (size_t)(m * 64 + w * 16 + r) * E_ + kc + kh * 32 + g * 8);
        #pragma unroll
        for (int rt = 0; rt < 2; ++rt)
          acc[m][rt] = __builtin_amdgcn_mfma_f32_16x16x32_bf16(a[rt], bf, acc[m][rt], 0, 0, 0);
      }
    }
  };

  stage(0, 0);
  asm volatile("s_waitcnt vmcnt(0)" ::: "memory");
  __syncthreads();
  for (int t = 0; t < 16; ++t) {
    const int buf = t & 1;
    if (t < 15) stage(buf ^ 1, (t + 1) * 64);
    compute(buf, t * 64);
    asm volatile("s_waitcnt vmcnt(0)" ::: "memory");
    __syncthreads();
  }

  // epilogue: reuse xs as per-wave repack space (32 rows x 24 cols bf16)
  __hip_bfloat16* rep = (__hip_bfloat16*)&xs[0][0][0] + w * (32 * 24);
  #pragma unroll
  for (int m = 0; m < 2; ++m) {
    __hip_bfloat16* Pout = (m == 0) ? Kb : Qb;
    #pragma unroll
    for (int rt = 0; rt < 2; ++rt)
      #pragma unroll
      for (int reg = 0; reg < 4; ++reg)
        rep[(rt * 16 + g * 4 + reg) * 24 + r] = __float2bfloat16(acc[m][rt][reg]);
    asm volatile("s_waitcnt lgkmcnt(0)" ::: "memory");
    __builtin_amdgcn_sched_barrier(0);
    {
      const int row = lane >> 1, ch = lane & 1;
      *(uint4*)(Pout + (size_t)(r0 + row) * H_ + w * 16 + ch * 8) =
          *(const uint4*)(rep + row * 24 + ch * 8);
    }
    asm volatile("s_waitcnt lgkmcnt(0)" ::: "memory");
    __builtin_amdgcn_sched_barrier(0);
  }
  // V: direct transposed write Vt[b][h][t]
  const int b = r0 >> 11;
  const int tt = r0 & 2047;
  #pragma unroll
  for (int rt = 0; rt < 2; ++rt) {
    ushort4 pk;
    pk.x = bfbits(acc[2][rt][0]); pk.y = bfbits(acc[2][rt][1]);
    pk.z = bfbits(acc[2][rt][2]); pk.w = bfbits(acc[2][rt][3]);
    *(ushort4*)(Vt + (size_t)(b * 64 + w * 16 + r) * T_ + tt + rt * 16 + g * 4) = pk;
  }
}

// ---- attention: barrier-free, swapped-QK, in-block key-split ----
// grid 1024 = 128 qtiles x 8 batches (blk = i*8+b pins batch b to XCD b)
// block = 2 waves; wave w handles key-tile range [t0,t1) of the 16-row qtile
__global__ __launch_bounds__(128, 2) void attn_mfma(
    const __hip_bfloat16* __restrict__ Qb, const __hip_bfloat16* __restrict__ Kb,
    const __hip_bfloat16* __restrict__ Vt, float* __restrict__ out) {
  __shared__ __hip_bfloat16 Ps[2][16][72];
  __shared__ float cmb[64][20];
  __shared__ float ml[16][2];
  const int tid = threadIdx.x;
  const int lane = tid & 63;
  const int w = tid >> 6;
  const int r = lane & 15, g = lane >> 4;
  const int blk = blockIdx.x;
  const int b = blk & 7;
  const int i = blk >> 3;  // 0..127
  const int s_ = i >> 5, j_ = i & 31;
  const int qt = (s_ == 0) ? j_ : (s_ == 1) ? (63 - j_) : (s_ == 2) ? (64 + j_) : (127 - j_);
  const int q0 = qt * 16;
  const size_t tb = (size_t)b * T_;
  const int bb = b * 64;

  // Q as Y-operand fragments: lane holds Q row q0+r, channels g*8 (+32)
  const short8v qf0 = *(const short8v*)(Qb + (tb + q0 + r) * H_ + g * 8);
  const short8v qf1 = *(const short8v*)(Qb + (tb + q0 + r) * H_ + 32 + g * 8);

  f32x4 o[4];
  #pragma unroll
  for (int k2 = 0; k2 < 4; ++k2) o[k2] = (f32x4){0.f, 0.f, 0.f, 0.f};
  float mrun = -1e30f, lrun = 0.f;

  const int nt = (qt >> 2) + 1;
  const int h_ = (nt + 1) >> 1;
  const int t0 = w ? h_ : 0;
  const int t1 = w ? nt : h_;

  short8v kbA[4][2], kbB[4][2];
  auto loadK = [&](int t, short8v (&kb)[4][2]) {
    #pragma unroll
    for (int kg = 0; kg < 4; ++kg)
      #pragma unroll
      for (int c = 0; c < 2; ++c)
        kb[kg][c] = *(const short8v*)(Kb + (tb + t * 64 + kg * 16 + r) * H_ + c * 32 + g * 8);
  };

  auto body = [&](int t, short8v (&kbU)[4][2], short8v (&kbP)[4][2]) {
    // issue V(t) early; used after softmax
    short8v vb[4][2];
    #pragma unroll
    for (int hg = 0; hg < 4; ++hg)
      #pragma unroll
      for (int c = 0; c < 2; ++c)
        vb[hg][c] = *(const short8v*)(
            Vt + (size_t)(bb + hg * 16 + r) * T_ + t * 64 + c * 32 + g * 8);
    if (t + 1 < t1) loadK(t + 1, kbP);  // prefetch next K

    // QK^T swapped: lane holds q = q0+r, keys kg*16 + g*4 + reg
    f32x4 s[4];
    #pragma unroll
    for (int k2 = 0; k2 < 4; ++k2) s[k2] = (f32x4){0.f, 0.f, 0.f, 0.f};
    __builtin_amdgcn_s_setprio(1);
    #pragma unroll
    for (int kg = 0; kg < 4; ++kg) {
      s[kg] = __builtin_amdgcn_mfma_f32_16x16x32_bf16(kbU[kg][0], qf0, s[kg], 0, 0, 0);
      s[kg] = __builtin_amdgcn_mfma_f32_16x16x32_bf16(kbU[kg][1], qf1, s[kg], 0, 0, 0);
    }
    __builtin_amdgcn_s_setprio(0);

    if (t == nt - 1) {  // diagonal tile only
      #pragma unroll
      for (int kg = 0; kg < 4; ++kg)
        #pragma unroll
        for (int reg = 0; reg < 4; ++reg)
          if (t * 64 + kg * 16 + g * 4 + reg > q0 + r) s[kg][reg] = -1e30f;
    }

    // online softmax: all state lane-local (q = q0+r); reduce over 4 g-lanes
    float pm = s[0][0];
    #pragma unroll
    for (int kg = 0; kg < 4; ++kg)
      #pragma unroll
      for (int reg = 0; reg < 4; ++reg) pm = fmaxf(pm, s[kg][reg]);
    pm = fmaxf(pm, __shfl_xor(pm, 16));
    pm = fmaxf(pm, __shfl_xor(pm, 32));
    const float nm = fmaxf(mrun, pm);
    const float al = __expf(mrun - nm);
    mrun = nm;
    float p[4][4];
    float rs = 0.f;
    #pragma unroll
    for (int kg = 0; kg < 4; ++kg)
      #pragma unroll
      for (int reg = 0; reg < 4; ++reg) {
        p[kg][reg] = __expf(s[kg][reg] - nm);
        rs += p[kg][reg];
      }
    rs += __shfl_xor(rs, 16);
    rs += __shfl_xor(rs, 32);
    lrun = lrun * al + rs;
    #pragma unroll
    for (int hg = 0; hg < 4; ++hg) o[hg] *= al;

    // P -> Ps[q][key] (4 packed b64 writes), read back as PV Y-fragment
    #pragma unroll
    for (int kg = 0; kg < 4; ++kg) {
      ushort4 u;
      u.x = bfbits(p[kg][0]); u.y = bfbits(p[kg][1]);
      u.z = bfbits(p[kg][2]); u.w = bfbits(p[kg][3]);
      *(ushort4*)&Ps[w][r][kg * 16 + g * 4] = u;
    }
    short8v pf[2];
    pf[0] = *(const short8v*)&Ps[w][r][g * 8];
    pf[1] = *(const short8v*)&Ps[w][r][32 + g * 8];

    // PV: o[hg] (h = hg*16+g*4+reg, q = q0+r)
    __builtin_amdgcn_s_setprio(1);
    #pragma unroll
    for (int c = 0; c < 2; ++c)
      #pragma unroll
      for (int hg = 0; hg < 4; ++hg)
        o[hg] = __builtin_amdgcn_mfma_f32_16x16x32_bf16(vb[hg][c], pf[c], o[hg], 0, 0, 0);
    __builtin_amdgcn_s_setprio(0);
  };

  if (t0 < t1) {
    loadK(t0, kbA);
    int t = t0;
    while (true) {
      body(t, kbA, kbB);
      if (++t >= t1) break;
      body(t, kbB, kbA);
      if (++t >= t1) break;
    }
  }

  // combine the two waves' partials
  if (w == 1) {
    if (g == 0) { ml[r][0] = mrun; ml[r][1] = lrun; }
    #pragma unroll
    for (int hg = 0; hg < 4; ++hg) *(f32x4*)&cmb[lane][hg * 4] = o[hg];
  }
  __syncthreads();
  if (w == 0) {
    const float m1 = ml[r][0], l1 = ml[r][1];
    const float mm = fmaxf(mrun, m1);
    const float sc0 = __expf(mrun - mm), sc1 = __expf(m1 - mm);
    const float inv = 1.f / (lrun * sc0 + l1 * sc1);
    #pragma unroll
    for (int hg = 0; hg < 4; ++hg) {
      const f32x4 o1 = *(const f32x4*)&cmb[lane][hg * 4];
      f32x4 res = (o[hg] * sc0 + o1 * sc1) * inv;
      *(f32x4*)(out + (tb + q0 + r) * H_ + hg * 16 + g * 4) = res;
    }
  }
}

extern "C" void kernel_launch(void* const* d_in, const int* in_sizes, int n_in,
                              void* d_out, int out_size, void* d_ws, size_t ws_size,
                              hipStream_t stream) {
  const float* x  = (const float*)d_in[0];
  const float* Wk = (const float*)d_in[1];
  const float* Wq = (const float*)d_in[2];
  const float* Wv = (const float*)d_in[3];
  float* out = (float*)d_out;

  __hip_bfloat16* Qb = (__hip_bfloat16*)d_ws;
  __hip_bfloat16* Kb = Qb + (size_t)B_ * T_ * H_;
  __hip_bfloat16* Vt = Kb + (size_t)B_ * T_ * H_;   // [B][64][T]
  __hip_bfloat16* Wt = Vt + (size_t)B_ * T_ * H_;   // [3][64][1024]

  prep_wt<<<(3 * H_ * E_) / 256, 256, 0, stream>>>(Wk, Wq, Wv, Wt);
  proj_mfma<<<(B_ * T_) / 32, 256, 0, stream>>>(x, Wt, Qb, Kb, Vt);
  attn_mfma<<<B_ * (T_ / 16), 128, 0, stream>>>(Qb, Kb, Vt, out);
}